// Round 1
// baseline (322.278 us; speedup 1.0000x reference)
//
#include <hip/hip_runtime.h>

// BEV pooling: out[bin, c] = sum over points i with ranks_bev[i]==bin of
//                            depth_flat[ranks_depth[i]] * feat_flat[ranks_feat[i], c]
// ranks_bev is SORTED -> block-per-bin with binary search for the segment,
// no atomics, every output element written exactly once.

#define CHN 80
#define GROUPS 16              // point slots per block
#define TPG 20                 // threads per slot; each lane owns 4 channels (float4)
#define BLOCK (GROUPS * TPG)   // 320 threads = 5 waves

__device__ __forceinline__ int lower_bound_i32(const int* __restrict__ a, int n, int v) {
    int lo = 0, hi = n;
    while (lo < hi) {
        int mid = (lo + hi) >> 1;
        if (a[mid] < v) lo = mid + 1; else hi = mid;
    }
    return lo;
}

__global__ __launch_bounds__(BLOCK)
void bev_pool_kernel(const float* __restrict__ depth,
                     const float* __restrict__ feat,
                     const int* __restrict__ rd,
                     const int* __restrict__ rf,
                     const int* __restrict__ rb,
                     float* __restrict__ out,
                     int P) {
    const int bin = blockIdx.x;
    const int t = threadIdx.x;
    const int g = t / TPG;       // point slot 0..15
    const int l = t % TPG;       // channel-quad lane 0..19
    const int c = l * 4;

    // Segment [lo, hi) of points belonging to this bin (all threads redundantly;
    // loads are wave-uniform -> broadcast from cache).
    int lo = lower_bound_i32(rb, P, bin);
    int hi = lo + lower_bound_i32(rb + lo, P - lo, bin + 1);

    float4 acc = make_float4(0.f, 0.f, 0.f, 0.f);
    for (int i = lo + g; i < hi; i += GROUPS) {
        const int di = rd[i];
        const int fi = rf[i];
        const float d = depth[di];
        const float4 f = *reinterpret_cast<const float4*>(feat + (size_t)fi * CHN + c);
        acc.x += d * f.x;
        acc.y += d * f.y;
        acc.z += d * f.z;
        acc.w += d * f.w;
    }

    __shared__ float4 smem[GROUPS][TPG];
    smem[g][l] = acc;
    __syncthreads();

    if (t < TPG) {  // 20 threads finalize; 15 serial float4 adds is negligible
        float4 s = smem[0][t];
        #pragma unroll
        for (int gg = 1; gg < GROUPS; ++gg) {
            float4 v = smem[gg][t];
            s.x += v.x; s.y += v.y; s.z += v.z; s.w += v.w;
        }
        *reinterpret_cast<float4*>(out + (size_t)bin * CHN + t * 4) = s;
    }
}

extern "C" void kernel_launch(void* const* d_in, const int* in_sizes, int n_in,
                              void* d_out, int out_size, void* d_ws, size_t ws_size,
                              hipStream_t stream) {
    const float* depth = (const float*)d_in[0];
    const float* feat  = (const float*)d_in[1];
    const int*   rd    = (const int*)d_in[2];
    const int*   rf    = (const int*)d_in[3];
    const int*   rb    = (const int*)d_in[4];
    // d_in[5], d_in[6] (interval_starts/lengths) unused per reference; d_in[7] scalar total_bev.
    float* out = (float*)d_out;

    const int P = in_sizes[2];
    const int total_bev = out_size / CHN;   // 40000

    bev_pool_kernel<<<total_bev, BLOCK, 0, stream>>>(depth, feat, rd, rf, rb, out, P);
}

// Round 2
// 148.427 us; speedup vs baseline: 2.1713x; 2.1713x over previous
//
#include <hip/hip_runtime.h>

// BEV pooling: out[bin, c] = sum over points i with ranks_bev[i]==bin of
//                            depth_flat[ranks_depth[i]] * feat_flat[ranks_feat[i], c]
// ranks_bev is SORTED. Two phases:
//   1) point-centric boundary detection -> seg[b] = lower_bound(rb, b), stored in d_ws
//   2) block-per-bin gather + reduce, segment bounds read directly (no binary search)

#define CHN 80
#define GROUPS 16              // point slots per block
#define TPG 20                 // threads per slot; each lane owns 4 channels (float4)
#define BLOCK (GROUPS * TPG)   // 320 threads = 5 waves

__global__ __launch_bounds__(256)
void seg_starts_kernel(const int* __restrict__ rb, int* __restrict__ seg,
                       int P, int total_bev) {
    int i = blockIdx.x * blockDim.x + threadIdx.x;
    if (i >= P) return;
    int cur = rb[i];
    int prev = (i == 0) ? -1 : rb[i - 1];
    // seg[b] = first index with rb[idx] >= b  (lower bound). For prev < b <= cur that's i.
    for (int b = prev + 1; b <= cur; ++b) seg[b] = i;
    if (i == P - 1) {
        for (int b = cur + 1; b <= total_bev; ++b) seg[b] = P;
    }
}

__global__ __launch_bounds__(BLOCK)
void bev_pool_kernel(const float* __restrict__ depth,
                     const float* __restrict__ feat,
                     const int* __restrict__ rd,
                     const int* __restrict__ rf,
                     const int* __restrict__ seg,
                     float* __restrict__ out) {
    const int bin = blockIdx.x;
    const int t = threadIdx.x;
    const int g = t / TPG;       // point slot 0..15
    const int l = t % TPG;       // channel-quad lane 0..19
    const int c = l * 4;

    const int lo = seg[bin];
    const int hi = seg[bin + 1];

    float4 acc = make_float4(0.f, 0.f, 0.f, 0.f);
    for (int i = lo + g; i < hi; i += GROUPS) {
        const int di = rd[i];
        const int fi = rf[i];
        const float d = depth[di];
        const float4 f = *reinterpret_cast<const float4*>(feat + (size_t)fi * CHN + c);
        acc.x += d * f.x;
        acc.y += d * f.y;
        acc.z += d * f.z;
        acc.w += d * f.w;
    }

    __shared__ float4 smem[GROUPS][TPG];
    smem[g][l] = acc;
    __syncthreads();

    if (t < TPG) {  // 20 threads finalize; 15 serial float4 adds is negligible
        float4 s = smem[0][t];
        #pragma unroll
        for (int gg = 1; gg < GROUPS; ++gg) {
            float4 v = smem[gg][t];
            s.x += v.x; s.y += v.y; s.z += v.z; s.w += v.w;
        }
        *reinterpret_cast<float4*>(out + (size_t)bin * CHN + t * 4) = s;
    }
}

extern "C" void kernel_launch(void* const* d_in, const int* in_sizes, int n_in,
                              void* d_out, int out_size, void* d_ws, size_t ws_size,
                              hipStream_t stream) {
    const float* depth = (const float*)d_in[0];
    const float* feat  = (const float*)d_in[1];
    const int*   rd    = (const int*)d_in[2];
    const int*   rf    = (const int*)d_in[3];
    const int*   rb    = (const int*)d_in[4];
    // d_in[5], d_in[6] (interval_starts/lengths) unused per reference; d_in[7] scalar total_bev.
    float* out = (float*)d_out;

    const int P = in_sizes[2];
    const int total_bev = out_size / CHN;   // 40000

    int* seg = (int*)d_ws;                  // total_bev+1 ints, rewritten fully every call

    seg_starts_kernel<<<(P + 255) / 256, 256, 0, stream>>>(rb, seg, P, total_bev);
    bev_pool_kernel<<<total_bev, BLOCK, 0, stream>>>(depth, feat, rd, rf, seg, out);
}

// Round 4
// 129.571 us; speedup vs baseline: 2.4873x; 1.1455x over previous
//
#include <hip/hip_runtime.h>

// BEV pooling: out[bin, c] = sum over points i with ranks_bev[i]==bin of
//                            depth_flat[ranks_depth[i]] * feat_flat[ranks_feat[i], c]
// ranks_bev is SORTED. Two phases:
//   1) seg[b] = lower_bound(rb, b) via vectorized boundary detection (int4)
//   2) ONE WAVE PER BIN: 64 lanes = 3 point-slots x 20 channel-quads (float4),
//      software-pipelined gather, shfl cross-slot reduce. No LDS, no barriers.
// R3 bug fixed: cross-slot shfl reduce must read BOTH slot partials before
// accumulating (sequential acc+=shfl(acc,...) made the 2nd shuffle read
// already-updated values, wrapping mod 64 into wrong lanes).

#define CHN 80

__global__ __launch_bounds__(256)
void seg_starts_kernel(const int* __restrict__ rb, int* __restrict__ seg,
                       int P, int total_bev) {
    int q = blockIdx.x * blockDim.x + threadIdx.x;   // quad index
    int i4 = q * 4;
    if (i4 >= P) return;
    const int4 v = *reinterpret_cast<const int4*>(rb + i4);
    int prev = (i4 == 0) ? -1 : rb[i4 - 1];
    int cur;
    cur = v.x; for (int b = prev + 1; b <= cur; ++b) seg[b] = i4 + 0; prev = cur;
    cur = v.y; for (int b = prev + 1; b <= cur; ++b) seg[b] = i4 + 1; prev = cur;
    cur = v.z; for (int b = prev + 1; b <= cur; ++b) seg[b] = i4 + 2; prev = cur;
    cur = v.w; for (int b = prev + 1; b <= cur; ++b) seg[b] = i4 + 3; prev = cur;
    if (i4 + 4 >= P) {
        for (int b = prev + 1; b <= total_bev; ++b) seg[b] = P;
    }
}

__global__ __launch_bounds__(256)
void bev_pool_kernel(const float* __restrict__ depth,
                     const float* __restrict__ feat,
                     const int* __restrict__ rd,
                     const int* __restrict__ rf,
                     const int* __restrict__ seg,
                     float* __restrict__ out,
                     int total_bev) {
    const int wave = threadIdx.x >> 6;               // 4 waves per block
    const int lane = threadIdx.x & 63;
    const int bin = blockIdx.x * 4 + wave;
    if (bin >= total_bev) return;

    const int slot = lane / 20;                      // 0..2 active, 3 = idle lanes 60-63
    const int l    = lane % 20;                      // channel-quad index
    const int c    = l * 4;

    const int lo = seg[bin];
    const int hi = seg[bin + 1];

    float4 acc = make_float4(0.f, 0.f, 0.f, 0.f);

    // Software-pipelined gather: next iteration's index loads issue before the
    // current iteration's data loads are consumed (overlaps the 2-level chain).
    int i = lo + slot;
    bool valid = (slot < 3) && (i < hi);
    int di = 0, fi = 0;
    if (valid) { di = rd[i]; fi = rf[i]; }
    while (valid) {
        const int ni = i + 3;
        const bool nvalid = ni < hi;
        int ndi = 0, nfi = 0;
        if (nvalid) { ndi = rd[ni]; nfi = rf[ni]; }          // prefetch next idx
        const float d  = depth[di];
        const float4 f = *reinterpret_cast<const float4*>(feat + (size_t)fi * CHN + c);
        acc.x += d * f.x;
        acc.y += d * f.y;
        acc.z += d * f.z;
        acc.w += d * f.w;
        i = ni; di = ndi; fi = nfi; valid = nvalid;
    }

    // Cross-slot reduce: read BOTH partials from the pre-reduce acc, then add.
    // Lanes 0-19 consume; shuffles from lanes 20-59 carry original slot sums.
    const float sx1 = __shfl(acc.x, lane + 20, 64);
    const float sy1 = __shfl(acc.y, lane + 20, 64);
    const float sz1 = __shfl(acc.z, lane + 20, 64);
    const float sw1 = __shfl(acc.w, lane + 20, 64);
    const float sx2 = __shfl(acc.x, lane + 40, 64);
    const float sy2 = __shfl(acc.y, lane + 40, 64);
    const float sz2 = __shfl(acc.z, lane + 40, 64);
    const float sw2 = __shfl(acc.w, lane + 40, 64);
    acc.x += sx1 + sx2;
    acc.y += sy1 + sy2;
    acc.z += sz1 + sz2;
    acc.w += sw1 + sw2;

    if (lane < 20) {
        *reinterpret_cast<float4*>(out + (size_t)bin * CHN + c) = acc;
    }
}

extern "C" void kernel_launch(void* const* d_in, const int* in_sizes, int n_in,
                              void* d_out, int out_size, void* d_ws, size_t ws_size,
                              hipStream_t stream) {
    const float* depth = (const float*)d_in[0];
    const float* feat  = (const float*)d_in[1];
    const int*   rd    = (const int*)d_in[2];
    const int*   rf    = (const int*)d_in[3];
    const int*   rb    = (const int*)d_in[4];
    // d_in[5], d_in[6] (interval_starts/lengths) unused per reference; d_in[7] scalar total_bev.
    float* out = (float*)d_out;

    const int P = in_sizes[2];
    const int total_bev = out_size / CHN;   // 40000

    int* seg = (int*)d_ws;                  // total_bev+1 ints, rewritten fully every call

    const int quads = (P + 3) / 4;
    seg_starts_kernel<<<(quads + 255) / 256, 256, 0, stream>>>(rb, seg, P, total_bev);
    bev_pool_kernel<<<(total_bev + 3) / 4, 256, 0, stream>>>(depth, feat, rd, rf, seg,
                                                             out, total_bev);
}

// Round 5
// 119.373 us; speedup vs baseline: 2.6998x; 1.0854x over previous
//
#include <hip/hip_runtime.h>

// BEV pooling: out[bin, c] = sum over points i with ranks_bev[i]==bin of
//                            depth_flat[ranks_depth[i]] * feat_flat[ranks_feat[i], c]
// ranks_bev is SORTED. Two phases:
//   1) seg[b] = lower_bound(rb, b) via vectorized boundary detection (int4)
//   2) ONE WAVE PER BIN, 16 point-slots x 4 channel-lanes: each lane owns 20
//      channels (5 x float4), so a wave ingests 16 points per iteration
//      (avg segment = 37.5 pts -> ~2.3 serial iterations instead of 12.5).
//      Cross-slot reduce = 4-level shfl_xor butterfly; coalesced 20-lane store.

#define CHN 80

__global__ __launch_bounds__(256)
void seg_starts_kernel(const int* __restrict__ rb, int* __restrict__ seg,
                       int P, int total_bev) {
    int q = blockIdx.x * blockDim.x + threadIdx.x;   // quad index
    int i4 = q * 4;
    if (i4 >= P) return;
    const int4 v = *reinterpret_cast<const int4*>(rb + i4);
    int prev = (i4 == 0) ? -1 : rb[i4 - 1];
    int cur;
    cur = v.x; for (int b = prev + 1; b <= cur; ++b) seg[b] = i4 + 0; prev = cur;
    cur = v.y; for (int b = prev + 1; b <= cur; ++b) seg[b] = i4 + 1; prev = cur;
    cur = v.z; for (int b = prev + 1; b <= cur; ++b) seg[b] = i4 + 2; prev = cur;
    cur = v.w; for (int b = prev + 1; b <= cur; ++b) seg[b] = i4 + 3; prev = cur;
    if (i4 + 4 >= P) {
        for (int b = prev + 1; b <= total_bev; ++b) seg[b] = P;
    }
}

__global__ __launch_bounds__(256)
void bev_pool_kernel(const float* __restrict__ depth,
                     const float* __restrict__ feat,
                     const int* __restrict__ rd,
                     const int* __restrict__ rf,
                     const int* __restrict__ seg,
                     float* __restrict__ out,
                     int total_bev) {
    const int wave = threadIdx.x >> 6;               // 4 waves per block
    const int lane = threadIdx.x & 63;
    const int bin = blockIdx.x * 4 + wave;
    if (bin >= total_bev) return;

    const int slot = lane >> 2;                      // 0..15 point slot
    const int ll   = lane & 3;                       // 0..3 channel sub-lane

    const int lo = seg[bin];
    const int hi = seg[bin + 1];

    float4 a0 = make_float4(0.f, 0.f, 0.f, 0.f);
    float4 a1 = a0, a2 = a0, a3 = a0, a4 = a0;

    // One-ahead index prefetch; rd/rf for a wave-iter are one 64B line.
    int i = lo + slot;
    bool valid = i < hi;
    int di = 0, fi = 0;
    if (valid) { di = rd[i]; fi = rf[i]; }
    while (valid) {
        const int ni = i + 16;
        const bool nvalid = ni < hi;
        int ndi = 0, nfi = 0;
        if (nvalid) { ndi = rd[ni]; nfi = rf[ni]; }

        const float d = depth[di];
        const float4* frow = reinterpret_cast<const float4*>(feat + (size_t)fi * CHN) + ll;
        const float4 f0 = frow[0];     // chunk ll      (floats  ll*4 .. ll*4+3)
        const float4 f1 = frow[4];     // chunk ll+4
        const float4 f2 = frow[8];
        const float4 f3 = frow[12];
        const float4 f4 = frow[16];
        a0.x += d * f0.x; a0.y += d * f0.y; a0.z += d * f0.z; a0.w += d * f0.w;
        a1.x += d * f1.x; a1.y += d * f1.y; a1.z += d * f1.z; a1.w += d * f1.w;
        a2.x += d * f2.x; a2.y += d * f2.y; a2.z += d * f2.z; a2.w += d * f2.w;
        a3.x += d * f3.x; a3.y += d * f3.y; a3.z += d * f3.z; a3.w += d * f3.w;
        a4.x += d * f4.x; a4.y += d * f4.y; a4.z += d * f4.z; a4.w += d * f4.w;

        i = ni; di = ndi; fi = nfi; valid = nvalid;
    }

    // Butterfly reduce across the 16 slots (lane bits 2..5). XOR butterfly is
    // self-symmetric, so in-place += is correct at every level.
    #pragma unroll
    for (int ofs = 4; ofs <= 32; ofs <<= 1) {
        a0.x += __shfl_xor(a0.x, ofs, 64); a0.y += __shfl_xor(a0.y, ofs, 64);
        a0.z += __shfl_xor(a0.z, ofs, 64); a0.w += __shfl_xor(a0.w, ofs, 64);
        a1.x += __shfl_xor(a1.x, ofs, 64); a1.y += __shfl_xor(a1.y, ofs, 64);
        a1.z += __shfl_xor(a1.z, ofs, 64); a1.w += __shfl_xor(a1.w, ofs, 64);
        a2.x += __shfl_xor(a2.x, ofs, 64); a2.y += __shfl_xor(a2.y, ofs, 64);
        a2.z += __shfl_xor(a2.z, ofs, 64); a2.w += __shfl_xor(a2.w, ofs, 64);
        a3.x += __shfl_xor(a3.x, ofs, 64); a3.y += __shfl_xor(a3.y, ofs, 64);
        a3.z += __shfl_xor(a3.z, ofs, 64); a3.w += __shfl_xor(a3.w, ofs, 64);
        a4.x += __shfl_xor(a4.x, ofs, 64); a4.y += __shfl_xor(a4.y, ofs, 64);
        a4.z += __shfl_xor(a4.z, ofs, 64); a4.w += __shfl_xor(a4.w, ofs, 64);
    }

    // Lane L (< 20) stores chunk L = j*4 + ll with j = L>>2  ->  its a[j].
    if (lane < 20) {
        const int j = lane >> 2;
        float4 w = a0;
        if (j == 1) w = a1;
        else if (j == 2) w = a2;
        else if (j == 3) w = a3;
        else if (j == 4) w = a4;
        *reinterpret_cast<float4*>(out + (size_t)bin * CHN + lane * 4) = w;
    }
}

extern "C" void kernel_launch(void* const* d_in, const int* in_sizes, int n_in,
                              void* d_out, int out_size, void* d_ws, size_t ws_size,
                              hipStream_t stream) {
    const float* depth = (const float*)d_in[0];
    const float* feat  = (const float*)d_in[1];
    const int*   rd    = (const int*)d_in[2];
    const int*   rf    = (const int*)d_in[3];
    const int*   rb    = (const int*)d_in[4];
    // d_in[5], d_in[6] (interval_starts/lengths) unused per reference; d_in[7] scalar total_bev.
    float* out = (float*)d_out;

    const int P = in_sizes[2];
    const int total_bev = out_size / CHN;   // 40000

    int* seg = (int*)d_ws;                  // total_bev+1 ints, rewritten fully every call

    const int quads = (P + 3) / 4;
    seg_starts_kernel<<<(quads + 255) / 256, 256, 0, stream>>>(rb, seg, P, total_bev);
    bev_pool_kernel<<<(total_bev + 3) / 4, 256, 0, stream>>>(depth, feat, rd, rf, seg,
                                                             out, total_bev);
}